// Round 12
// baseline (829.946 us; speedup 1.0000x reference)
//
#include <hip/hip_runtime.h>
#include <math.h>

// ---------------- problem dims ----------------
#define NB 32
#define NT 64
#define NF 2048  // NB*NT frames

// ---------------- output float offsets ----------------
#define OUT_ZS    2097152
#define OUT_PRM   (OUT_ZS + 65536)
#define OUT_PRLS  (OUT_PRM + 65536)
#define OUT_PM    (OUT_PRLS + 65536)
#define OUT_PLS   (OUT_PM + 65536)
#define OUT_HF    (OUT_PLS + 65536)

// ---------------- workspace float offsets ----------------
#define WS_HS    27394048   // 64*32*128
#define WS_ENCT  27656192   // enc_pw^T (1024x64)
#define WS_DECB  27721728   // dec_pw bf16 [out][k] (1024x160 us = 81920 f)
#define WS_WP1H  27885568   // 128x128 bf16
#define WS_WP2   27893760   // 128x128 bf16
#define WS_WP3   27901952   // 64x128 bf16
#define WS_WWHH  27906048   // 384x128 bf16
#define WS_WIHZ  27930624   // 384x32 bf16
#define WS_QW1T  27936768   // 130x128
#define WS_QW2T  27953408   // 128x128
#define WS_QW3T  27969792   // 128x64
#define WS_PW1T  27977984   // 192x128
#define WS_WIHT  28002560   // 34x384
#define WS_WC2   16777216   // 16*64*32 bf16
#define WS_WC3   (WS_WC2 + 16384)
#define WS_WD1   (WS_WC3 + 32768)
#define WS_WD2   (WS_WD1 + 32768)
#define WS_POSL1E 25165824  // 2048*128
#define WS_GIA    (WS_POSL1E + 262144)  // 2048*384

// ==================== helpers ====================
typedef __attribute__((ext_vector_type(8))) short short8;
typedef __attribute__((ext_vector_type(4))) float floatx4;
union U4S8 { uint4 u; short8 s; };
__device__ __forceinline__ short8 u2s(uint4 u) { U4S8 x; x.u = u; return x.s; }
__device__ __forceinline__ float eluf(float a) { return (a > 0.f) ? a : expm1f(a); }
__device__ __forceinline__ float sigm(float a) { return 1.f / (1.f + expf(-a)); }
__device__ __forceinline__ unsigned short f2bf(float f) {
  unsigned int u = __float_as_uint(f);
  u += 0x7fffu + ((u >> 16) & 1u);
  return (unsigned short)(u >> 16);
}
__device__ __forceinline__ float bf2f(unsigned short s) {
  return __uint_as_float(((unsigned int)s) << 16);
}
__device__ __forceinline__ float dotp8(uint4 u, const float* __restrict__ x) {
  float4 x0 = *reinterpret_cast<const float4*>(x);
  float4 x1 = *reinterpret_cast<const float4*>(x + 4);
  float acc;
  acc  = __uint_as_float(u.x << 16) * x0.x;
  acc += __uint_as_float(u.x & 0xffff0000u) * x0.y;
  acc += __uint_as_float(u.y << 16) * x0.z;
  acc += __uint_as_float(u.y & 0xffff0000u) * x0.w;
  acc += __uint_as_float(u.z << 16) * x1.x;
  acc += __uint_as_float(u.z & 0xffff0000u) * x1.y;
  acc += __uint_as_float(u.w << 16) * x1.z;
  acc += __uint_as_float(u.w & 0xffff0000u) * x1.w;
  return acc;
}

// ==================== unified prep: fp32 transposes + bf16 packs ===========
// mode 10: fp32 transpose dst[c*A+r]=src[r*B+c]
// mode 0: bf16 direct; 1: pos_w1 h-part; 2: wih z-part;
// mode 3: conv w [oc][ic][t]->[t][oc][ic]; 4: deconv w [ic][oc][t]->[t][oc][ic]
struct PP { const float* src; void* dst; int n; int mode; int A; int B; };
struct PPAll { PP m[16]; };

__global__ __launch_bounds__(256) void k_prep(PPAll a) {
  PP p = a.m[blockIdx.y];
  for (int i = blockIdx.x * 256 + threadIdx.x; i < p.n; i += gridDim.x * 256) {
    if (p.mode == 10) {
      const int r = i / p.B, c = i - r * p.B;
      ((float*)p.dst)[c * p.A + r] = p.src[i];
    } else {
      float v;
      if (p.mode == 0) v = p.src[i];
      else if (p.mode == 1) v = p.src[(i >> 7) * 192 + (i & 127)];
      else if (p.mode == 2) v = p.src[(i >> 5) * 34 + (i & 31)];
      else {
        const int ab = p.A * p.B;
        const int t = i / ab, rem = i - t * ab;
        const int oc = rem / p.B, ic = rem - oc * p.B;
        v = (p.mode == 3) ? p.src[(oc * p.B + ic) * 16 + t]
                          : p.src[(ic * p.A + oc) * 16 + t];
      }
      ((unsigned short*)p.dst)[i] = f2bf(v);
    }
  }
}

// ==================== fused encoder: conv1->conv2->conv3->enclin->pre ======
// one block per frame f = b*64+t ; all activations LDS-resident.
__global__ __launch_bounds__(256, 2) void k_enc(
    const float* __restrict__ obs, const float* __restrict__ act,
    const float* __restrict__ w1, const float* __restrict__ b1,
    const unsigned short* __restrict__ wc2, const float* __restrict__ b2,
    const unsigned short* __restrict__ wc3, const float* __restrict__ b3,
    const float* __restrict__ encT, const float* __restrict__ encb,
    const float* __restrict__ pw1T, const float* __restrict__ pb1,
    const float* __restrict__ wihT, const float* __restrict__ bih,
    float* __restrict__ posl1e, float* __restrict__ gia) {
  const int f = blockIdx.x, tid = threadIdx.x;
  const int w = tid >> 6, l = tid & 63, q = l >> 4, n = l & 15;
  __shared__ float sIn1[32 * 33];
  __shared__ float sW1[512];
  __shared__ float sB1[32];
  __shared__ __align__(16) unsigned short sIn2[18 * 18 * 40];  // conv2 haloed in
  __shared__ __align__(16) unsigned short sIn3[10 * 10 * 72];  // conv3 haloed in
  __shared__ __align__(16) float sXe[1024];                    // enclin in [ch*16+px]
  __shared__ float sP[256];
  __shared__ float sE[64];
  __shared__ float sA2[2];

  // ---- stage conv1 inputs + zero haloed buffers
  {
    const float* in = obs + (size_t)f * 1024;
    for (int i = tid; i < 1024; i += 256) sIn1[(i >> 5) * 33 + (i & 31)] = in[i];
    for (int i = tid; i < 512; i += 256) sW1[i] = w1[i];
    if (tid < 32) sB1[tid] = b1[tid];
    if (tid < 2) sA2[tid] = act[(size_t)f * 2 + tid];
    unsigned int* z2 = (unsigned int*)sIn2;
    for (int i = tid; i < 18 * 18 * 40 / 2; i += 256) z2[i] = 0u;
    unsigned int* z3 = (unsigned int*)sIn3;
    for (int i = tid; i < 10 * 10 * 72 / 2; i += 256) z3[i] = 0u;
  }
  __syncthreads();
  // ---- conv1 (fp32) -> sIn2 interior
  for (int r = tid; r < 512; r += 256) {       // r = oc*16 + oy
    const int oc = r >> 4, oy = r & 15;
    float acc[16];
    const float bv = sB1[oc];
#pragma unroll
    for (int j = 0; j < 16; j++) acc[j] = bv;
#pragma unroll
    for (int ky = 0; ky < 4; ky++) {
      const int iy = 2 * oy + ky - 1;
      if (iy < 0 || iy >= 32) continue;
#pragma unroll
      for (int kx = 0; kx < 4; kx++) {
        const float wv = sW1[oc * 16 + ky * 4 + kx];
#pragma unroll
        for (int j = 0; j < 16; j++) {
          const int ix = 2 * j + kx - 1;
          if (ix >= 0 && ix < 32) acc[j] += wv * sIn1[iy * 33 + ix];
        }
      }
    }
#pragma unroll
    for (int j = 0; j < 16; j++)
      sIn2[((oy + 1) * 18 + (j + 1)) * 40 + oc] = f2bf(fmaxf(acc[j], 0.f));
  }
  __syncthreads();
  // ---- conv2 MFMA (IC=32 OC=64, 16x16 out) -> sIn3 interior
  {
    int base[4];
#pragma unroll
    for (int nt = 0; nt < 4; nt++) {
      const int px = nt * 16 + n, oy = px >> 3, ox = px & 7;
      base[nt] = ((2 * oy + 1) * 18 + (2 * ox + 1)) * 40 + q * 8;
    }
    floatx4 acc[4];
#pragma unroll
    for (int nt = 0; nt < 4; nt++) acc[nt] = (floatx4){0.f, 0.f, 0.f, 0.f};
    uint4 af[16];
#pragma unroll
    for (int t = 0; t < 16; t++)
      af[t] = *reinterpret_cast<const uint4*>(wc2 + (size_t)(t * 64 + w * 16 + n) * 32 + q * 8);
#pragma unroll
    for (int t = 0; t < 16; t++) {
      const int toff = ((t / 4 - 1) * 18 + (t % 4 - 1)) * 40;
#pragma unroll
      for (int nt = 0; nt < 4; nt++) {
        uint4 bf = *reinterpret_cast<const uint4*>(&sIn2[base[nt] + toff]);
        acc[nt] = __builtin_amdgcn_mfma_f32_16x16x32_bf16(u2s(af[t]), u2s(bf), acc[nt], 0, 0, 0);
      }
    }
    float b4[4];
#pragma unroll
    for (int r = 0; r < 4; r++) b4[r] = b2[w * 16 + q * 4 + r];
    __syncthreads();
#pragma unroll
    for (int nt = 0; nt < 4; nt++) {
      const int px = nt * 16 + n, oy = px >> 3, ox = px & 7;
#pragma unroll
      for (int r = 0; r < 4; r++)
        sIn3[((oy + 1) * 10 + (ox + 1)) * 72 + (w * 16 + q * 4 + r)] =
            f2bf(fmaxf(acc[nt][r] + b4[r], 0.f));
    }
  }
  __syncthreads();
  // ---- conv3 MFMA (IC=64 OC=64, 4x4 out) -> sXe fp32 [ch*16+px]
  {
    const int oy = n >> 2, ox = n & 3;
    const int ibase = ((2 * oy + 1) * 10 + (2 * ox + 1)) * 72 + q * 8;
    floatx4 acc = (floatx4){0.f, 0.f, 0.f, 0.f};
    for (int ks = 0; ks < 2; ks++) {
      uint4 af[16];
#pragma unroll
      for (int t = 0; t < 16; t++)
        af[t] = *reinterpret_cast<const uint4*>(
            wc3 + (size_t)(t * 64 + w * 16 + n) * 64 + ks * 32 + q * 8);
#pragma unroll
      for (int t = 0; t < 16; t++) {
        const int toff = ((t / 4 - 1) * 10 + (t % 4 - 1)) * 72 + ks * 32;
        uint4 bf = *reinterpret_cast<const uint4*>(&sIn3[ibase + toff]);
        acc = __builtin_amdgcn_mfma_f32_16x16x32_bf16(u2s(af[t]), u2s(bf), acc, 0, 0, 0);
      }
    }
#pragma unroll
    for (int r = 0; r < 4; r++) {
      const int ch = w * 16 + q * 4 + r;
      sXe[ch * 16 + n] = fmaxf(acc[r] + b3[ch], 0.f);
    }
  }
  __syncthreads();
  // ---- enclin -> sE[64]
  {
    const int o = tid & 63, s = tid >> 6;
    float acc = 0.f;
    const int k0 = s * 256;
    for (int k = k0; k < k0 + 256; k++) acc += encT[k * 64 + o] * sXe[k];
    sP[tid] = acc;
  }
  __syncthreads();
  if (tid < 64)
    sE[tid] = sP[tid] + sP[tid + 64] + sP[tid + 128] + sP[tid + 192] + encb[tid];
  __syncthreads();
  // ---- pre: posl1e (e-part) + gia (a-part)
  if (tid < 128) {
    float a = pb1[tid];
    for (int k = 0; k < 64; k++) a += pw1T[(128 + k) * 128 + tid] * sE[k];
    posl1e[(size_t)f * 128 + tid] = a;
  } else {
#pragma unroll
    for (int jj = 0; jj < 3; jj++) {
      const int j = (tid - 128) + jj * 128;
      gia[(size_t)f * 384 + j] =
          bih[j] + wihT[32 * 384 + j] * sA2[0] + wihT[33 * 384 + j] * sA2[1];
    }
  }
}

// ==================== recurrent core (round-9 winner) ======================
__global__ __launch_bounds__(512, 2) void k_rssm4(
    const float* __restrict__ posl1e, const float* __restrict__ gia,
    const float* __restrict__ noise,
    const unsigned short* __restrict__ wp1h, const unsigned short* __restrict__ wp2,
    const unsigned short* __restrict__ wp3, const unsigned short* __restrict__ wwhh,
    const unsigned short* __restrict__ wihz,
    const float* __restrict__ pb2, const float* __restrict__ pb3,
    const float* __restrict__ bhh,
    float* __restrict__ hs, float* __restrict__ out) {
  const int b = blockIdx.x, tid = threadIdx.x;
  __shared__ __align__(16) float sH[128], sL1[128], sL2[128];
  __shared__ __align__(16) float sGh[384], sGi[384], sZ[32];
  __shared__ __align__(16) float sPart[512];
  uint4 wA[16], wB[4], wC[2], wD[4];
  {
    const unsigned short* rowA =
        (tid < 128) ? (wp1h + tid * 128) : (wwhh + (size_t)(tid - 128) * 128);
#pragma unroll
    for (int i = 0; i < 16; i++) wA[i] = reinterpret_cast<const uint4*>(rowA)[i];
    const unsigned short* rowB = wp2 + (tid & 127) * 128 + (tid >> 7) * 32;
#pragma unroll
    for (int i = 0; i < 4; i++) wB[i] = reinterpret_cast<const uint4*>(rowB)[i];
    const unsigned short* rowC = wp3 + (tid & 63) * 128 + (tid >> 6) * 16;
#pragma unroll
    for (int i = 0; i < 2; i++) wC[i] = reinterpret_cast<const uint4*>(rowC)[i];
    if (tid < 384) {
      const unsigned short* rowD = wihz + (size_t)tid * 32;
#pragma unroll
      for (int i = 0; i < 4; i++) wD[i] = reinterpret_cast<const uint4*>(rowD)[i];
    }
  }
  const float bhhR = (tid >= 128) ? bhh[tid - 128] : 0.f;
  const float pb2R = (tid < 128) ? pb2[tid] : 0.f;
  const float pb3mR = (tid < 32) ? pb3[tid] : 0.f;
  const float pb3sR = (tid < 32) ? pb3[tid + 32] : 0.f;
  float pl1R = 0.f, giaR = 0.f, epsR = 0.f;
  if (tid < 128) {
    pl1R = posl1e[(size_t)(b * 64) * 128 + tid];
    sH[tid] = 0.f;
    hs[(size_t)b * 128 + tid] = 0.f;
  }
  if (tid < 384) giaR = gia[(size_t)(b * 64) * 384 + tid];
  if (tid < 32) epsR = noise[(size_t)b * 32 + tid];

  for (int t = 0; t < 64; ++t) {
    __syncthreads();
    const int tn = (t < 63) ? t + 1 : 63;
    float pl1N = 0.f, giaN = 0.f, epsN = 0.f;
    if (tid < 128) pl1N = posl1e[(size_t)(b * 64 + tn) * 128 + tid];
    if (tid < 384) giaN = gia[(size_t)(b * 64 + tn) * 384 + tid];
    if (tid < 32) epsN = noise[(size_t)(tn * 32 + b) * 32 + tid];
    {
      float a = (tid < 128) ? pl1R : bhhR;
#pragma unroll
      for (int i = 0; i < 16; i++) a += dotp8(wA[i], sH + i * 8);
      if (tid < 128) sL1[tid] = eluf(a);
      else sGh[tid - 128] = a;
    }
    __syncthreads();
    {
      const float* xb = sL1 + (tid >> 7) * 32;
      float p = 0.f;
#pragma unroll
      for (int i = 0; i < 4; i++) p += dotp8(wB[i], xb + i * 8);
      sPart[tid] = p;
    }
    __syncthreads();
    if (tid < 128)
      sL2[tid] = eluf(pb2R + sPart[tid] + sPart[tid + 128] + sPart[tid + 256] +
                      sPart[tid + 384]);
    __syncthreads();
    {
      const float* xc = sL2 + (tid >> 6) * 16;
      sPart[tid] = dotp8(wC[0], xc) + dotp8(wC[1], xc + 8);
    }
    __syncthreads();
    if (tid < 32) {
      float pm = pb3mR, pls = pb3sR;
#pragma unroll
      for (int c = 0; c < 8; c++) {
        pm += sPart[c * 64 + tid];
        pls += sPart[c * 64 + 32 + tid];
      }
      pls = fminf(fmaxf(pls, -5.f), 2.f);
      const float z = pm + expf(pls) * epsR;
      sZ[tid] = z;
      const int o = (b * 64 + t) * 32 + tid;
      out[OUT_ZS + o] = z;
      out[OUT_PM + o] = pm;
      out[OUT_PLS + o] = pls;
    }
    __syncthreads();
    if (tid < 384) {
      float s = giaR;
#pragma unroll
      for (int i = 0; i < 4; i++) s += dotp8(wD[i], sZ + i * 8);
      sGi[tid] = s;
    }
    __syncthreads();
    if (tid < 128) {
      const float r = sigm(sGi[tid] + sGh[tid]);
      const float u = sigm(sGi[128 + tid] + sGh[128 + tid]);
      const float n = tanhf(sGi[256 + tid] + r * sGh[256 + tid]);
      const float hn = (1.f - u) * n + u * sH[tid];
      sH[tid] = hn;
      if (t < 63) hs[(size_t)((t + 1) * 32 + b) * 128 + tid] = hn;
    }
    pl1R = pl1N;
    giaR = giaN;
    epsR = epsN;
  }
  __syncthreads();
  if (tid < 128) out[OUT_HF + b * 128 + tid] = sH[tid];
}

// ==================== fused decoder + prior ================================
// one block per frame f = t*32+b ; declin->deconv1->deconv2->deconv3 + pri.
__global__ __launch_bounds__(256, 2) void k_dec(
    const float* __restrict__ hs, const float* __restrict__ zs,
    const float* __restrict__ act,
    const unsigned short* __restrict__ decB, const float* __restrict__ decb,
    const unsigned short* __restrict__ wd1, const float* __restrict__ db1,
    const unsigned short* __restrict__ wd2, const float* __restrict__ db2,
    const float* __restrict__ w3, const float* __restrict__ b3,
    const float* __restrict__ qw1T, const float* __restrict__ qb1,
    const float* __restrict__ qw2T, const float* __restrict__ qb2,
    const float* __restrict__ qw3T, const float* __restrict__ qb3,
    float* __restrict__ out) {
  const int f = blockIdx.x, tid = threadIdx.x;
  const int w = tid >> 6, l = tid & 63, q = l >> 4, n = l & 15;
  const int t = f >> 5, b = f & 31;
  __shared__ __align__(16) float sX[160];
  __shared__ __align__(16) unsigned short sInD1[6 * 6 * 72];    // deconv1 haloed in
  __shared__ __align__(16) unsigned short sInD2[10 * 10 * 72];  // deconv2 haloed in
  __shared__ unsigned short sInD3[32 * 273];                    // deconv3 in bf16 [ic][iy*17+ix]
  __shared__ float sW3[32 * 16 * 2];
  __shared__ float sPri1[128], sPri2[128];
  __shared__ float sA2[2];

  // ---- stage inputs + zero halos + stage deconv3 weights
  if (tid < 128) sX[tid] = hs[(size_t)f * 128 + tid];
  else if (tid < 160) sX[tid] = zs[(size_t)(b * 64 + t) * 32 + (tid - 128)];
  if (tid >= 160 && tid < 162) sA2[tid - 160] = act[(size_t)(b * 64 + t) * 2 + (tid - 160)];
  {
    unsigned int* z1 = (unsigned int*)sInD1;
    for (int i = tid; i < 6 * 6 * 72 / 2; i += 256) z1[i] = 0u;
    unsigned int* z2 = (unsigned int*)sInD2;
    for (int i = tid; i < 10 * 10 * 72 / 2; i += 256) z2[i] = 0u;
    for (int s = tid; s < 512; s += 256) {
      const int icc = s >> 4, tap = s & 15;
      sW3[(icc * 16 + tap) * 2] = w3[s];
    }
  }
  __syncthreads();
  // ---- declin (bf16 weights [out][k], K=160) -> sInD1 interior, bf16
  {
#pragma unroll
    for (int i = 0; i < 4; i++) {
      const int o = i * 256 + tid;
      float acc = decb[o];
      const unsigned short* wr = decB + (size_t)o * 160;
#pragma unroll
      for (int kk = 0; kk < 20; kk++)
        acc += dotp8(*reinterpret_cast<const uint4*>(wr + kk * 8), sX + kk * 8);
      const int c = o >> 4, px = o & 15;
      const int Y = px >> 2, X = px & 3;
      sInD1[((Y + 1) * 6 + (X + 1)) * 72 + c] = f2bf(acc);
    }
  }
  __syncthreads();
  // ---- deconv1 MFMA (IC=64 IH=IW=4 OC=64) -> sInD2 interior
  {
    const int Y = n >> 2, X = n & 3;
    const int ibase = ((Y + 1) * 6 + (X + 1)) * 72 + q * 8;
    float b4[4];
#pragma unroll
    for (int r = 0; r < 4; r++) b4[r] = db1[w * 16 + q * 4 + r];
#pragma unroll
    for (int c = 0; c < 4; c++) {
      const int cy = c >> 1, cx = c & 1;
      floatx4 acc = (floatx4){0.f, 0.f, 0.f, 0.f};
      for (int ks = 0; ks < 2; ks++) {
        uint4 af[4];
#pragma unroll
        for (int tt = 0; tt < 4; tt++) {
          const int t2 = tt >> 1, t3 = tt & 1;
          const int ky = ((cy + 1) & 1) + 2 * t2, kx = ((cx + 1) & 1) + 2 * t3;
          af[tt] = *reinterpret_cast<const uint4*>(
              wd1 + (size_t)((ky * 4 + kx) * 64 + w * 16 + n) * 64 + ks * 32 + q * 8);
        }
#pragma unroll
        for (int tt = 0; tt < 4; tt++) {
          const int t2 = tt >> 1, t3 = tt & 1;
          const int toff = ((cy - t2) * 6 + (cx - t3)) * 72 + ks * 32;
          uint4 bf = *reinterpret_cast<const uint4*>(&sInD1[ibase + toff]);
          acc = __builtin_amdgcn_mfma_f32_16x16x32_bf16(u2s(af[tt]), u2s(bf), acc, 0, 0, 0);
        }
      }
      const int oy = 2 * Y + cy, ox = 2 * X + cx;
#pragma unroll
      for (int r = 0; r < 4; r++)
        sInD2[((oy + 1) * 10 + (ox + 1)) * 72 + (w * 16 + q * 4 + r)] =
            f2bf(fmaxf(acc[r] + b4[r], 0.f));
    }
  }
  __syncthreads();
  // ---- deconv2 MFMA (IC=64 IH=IW=8 OC=32) -> sInD3 bf16
  {
    const int px = w * 16 + n;
    const int Y = px >> 3, X = px & 7;
    const int ibase = ((Y + 1) * 10 + (X + 1)) * 72 + q * 8;
    float b4[2][4];
#pragma unroll
    for (int mi = 0; mi < 2; mi++)
#pragma unroll
      for (int r = 0; r < 4; r++) b4[mi][r] = db2[mi * 16 + q * 4 + r];
#pragma unroll
    for (int c = 0; c < 4; c++) {
      const int cy = c >> 1, cx = c & 1;
      floatx4 acc[2];
      acc[0] = (floatx4){0.f, 0.f, 0.f, 0.f};
      acc[1] = (floatx4){0.f, 0.f, 0.f, 0.f};
      for (int ks = 0; ks < 2; ks++) {
        uint4 af[2][4];
#pragma unroll
        for (int mi = 0; mi < 2; mi++)
#pragma unroll
          for (int tt = 0; tt < 4; tt++) {
            const int t2 = tt >> 1, t3 = tt & 1;
            const int ky = ((cy + 1) & 1) + 2 * t2, kx = ((cx + 1) & 1) + 2 * t3;
            af[mi][tt] = *reinterpret_cast<const uint4*>(
                wd2 + (size_t)((ky * 4 + kx) * 32 + mi * 16 + n) * 64 + ks * 32 + q * 8);
          }
#pragma unroll
        for (int tt = 0; tt < 4; tt++) {
          const int t2 = tt >> 1, t3 = tt & 1;
          const int toff = ((cy - t2) * 10 + (cx - t3)) * 72 + ks * 32;
          uint4 bf = *reinterpret_cast<const uint4*>(&sInD2[ibase + toff]);
#pragma unroll
          for (int mi = 0; mi < 2; mi++)
            acc[mi] = __builtin_amdgcn_mfma_f32_16x16x32_bf16(u2s(af[mi][tt]), u2s(bf),
                                                              acc[mi], 0, 0, 0);
        }
      }
      const int oy = 2 * Y + cy, ox = 2 * X + cx;
#pragma unroll
      for (int mi = 0; mi < 2; mi++)
#pragma unroll
        for (int r = 0; r < 4; r++) {
          const int oc = mi * 16 + q * 4 + r;
          sInD3[oc * 273 + oy * 17 + ox] = f2bf(fmaxf(acc[mi][r] + b4[mi][r], 0.f));
        }
    }
  }
  __syncthreads();
  // ---- deconv3 (fp32, OC=1, sigmoid, REMAP) from sInD3  [+ pri st1 on 128-255? no: all 256 busy]
  {
    const int oy = tid >> 3;               // 0..31
    const int rem2 = tid & 7;
    const int cpar = rem2 >> 2, qq = rem2 & 3;
    const int py = (oy + 1) & 1, pc = (cpar + 1) & 1;
    float acc[4];
    const float bv = b3[0];
#pragma unroll
    for (int j = 0; j < 4; j++) acc[j] = bv;
    for (int icc = 0; icc < 32; icc++) {
      const unsigned short* inb = &sInD3[icc * 273];
      const float* wb = &sW3[icc * 32];
#pragma unroll
      for (int t2 = 0; t2 < 2; t2++) {
        const int ky = py + 2 * t2;
        const int iy = (oy + 1 - ky) >> 1;
        if (iy < 0 || iy >= 16) continue;
        const unsigned short* row = inb + iy * 17;
#pragma unroll
        for (int t3 = 0; t3 < 2; t3++) {
          const int kx = pc + 2 * t3;
          const int ixb = (cpar + 1 - kx) >> 1;
          const float wv = wb[(ky * 4 + kx) * 2];
#pragma unroll
          for (int j = 0; j < 4; j++) {
            const int ix = ixb + qq * 4 + j;
            if (ix >= 0 && ix < 16) acc[j] += wv * bf2f(row[ix]);
          }
        }
      }
    }
    const int fo = b * 64 + t;  // REMAP (t*32+b -> b*64+t)
    float* yf = out + (size_t)fo * 1024;
#pragma unroll
    for (int j = 0; j < 4; j++)
      yf[oy * 32 + (cpar + 2 * (qq * 4 + j))] = 1.f / (1.f + expf(-acc[j]));
  }
  // ---- prior chain (fp32, coalesced transposed weights); sX[0:128] = h
  __syncthreads();
  if (tid < 128) {
    float a = qb1[tid];
    for (int k = 0; k < 128; k++) a += qw1T[k * 128 + tid] * sX[k];
    a += qw1T[128 * 128 + tid] * sA2[0] + qw1T[129 * 128 + tid] * sA2[1];
    sPri1[tid] = eluf(a);
  }
  __syncthreads();
  if (tid < 128) {
    float a = qb2[tid];
    for (int k = 0; k < 128; k++) a += qw2T[k * 128 + tid] * sPri1[k];
    sPri2[tid] = eluf(a);
  }
  __syncthreads();
  if (tid < 64) {
    float a = qb3[tid];
    for (int k = 0; k < 128; k++) a += qw3T[k * 64 + tid] * sPri2[k];
    const int o = (b * 64 + t) * 32;
    if (tid < 32) out[OUT_PRM + o + tid] = a;
    else out[OUT_PRLS + o + tid - 32] = fminf(fmaxf(a, -5.f), 2.f);
  }
}

// ==================== launch ====================
extern "C" void kernel_launch(void* const* d_in, const int* in_sizes, int n_in,
                              void* d_out, int out_size, void* d_ws, size_t ws_size,
                              hipStream_t stream) {
  const float* obs = (const float*)d_in[0];
  const float* actions = (const float*)d_in[1];
  const float* noise = (const float*)d_in[2];
  const float* enc_w1 = (const float*)d_in[3];
  const float* enc_b1 = (const float*)d_in[4];
  const float* enc_w2 = (const float*)d_in[5];
  const float* enc_b2 = (const float*)d_in[6];
  const float* enc_w3 = (const float*)d_in[7];
  const float* enc_b3 = (const float*)d_in[8];
  const float* enc_pw = (const float*)d_in[9];
  const float* enc_pb = (const float*)d_in[10];
  const float* dec_pw = (const float*)d_in[11];
  const float* dec_pb = (const float*)d_in[12];
  const float* dec_w1 = (const float*)d_in[13];
  const float* dec_b1 = (const float*)d_in[14];
  const float* dec_w2 = (const float*)d_in[15];
  const float* dec_b2 = (const float*)d_in[16];
  const float* dec_w3 = (const float*)d_in[17];
  const float* dec_b3 = (const float*)d_in[18];
  const float* gru_wih = (const float*)d_in[19];
  const float* gru_whh = (const float*)d_in[20];
  const float* gru_bih = (const float*)d_in[21];
  const float* gru_bhh = (const float*)d_in[22];
  const float* pri_w1 = (const float*)d_in[23];
  const float* pri_b1 = (const float*)d_in[24];
  const float* pri_w2 = (const float*)d_in[25];
  const float* pri_b2 = (const float*)d_in[26];
  const float* pri_w3 = (const float*)d_in[27];
  const float* pri_b3 = (const float*)d_in[28];
  const float* pos_w1 = (const float*)d_in[29];
  const float* pos_b1 = (const float*)d_in[30];
  const float* pos_w2 = (const float*)d_in[31];
  const float* pos_b2 = (const float*)d_in[32];
  const float* pos_w3 = (const float*)d_in[33];
  const float* pos_b3 = (const float*)d_in[34];

  float* out = (float*)d_out;
  float* ws = (float*)d_ws;
  float* HS = ws + WS_HS;
  float* POSL1E = ws + WS_POSL1E;
  float* GIA = ws + WS_GIA;
  unsigned short* DECB = (unsigned short*)(ws + WS_DECB);
  unsigned short* WP1H = (unsigned short*)(ws + WS_WP1H);
  unsigned short* WP2 = (unsigned short*)(ws + WS_WP2);
  unsigned short* WP3 = (unsigned short*)(ws + WS_WP3);
  unsigned short* WWHH = (unsigned short*)(ws + WS_WWHH);
  unsigned short* WIHZ = (unsigned short*)(ws + WS_WIHZ);
  unsigned short* WC2 = (unsigned short*)(ws + WS_WC2);
  unsigned short* WC3 = (unsigned short*)(ws + WS_WC3);
  unsigned short* WD1 = (unsigned short*)(ws + WS_WD1);
  unsigned short* WD2 = (unsigned short*)(ws + WS_WD2);

  // unified prep: 6 fp32 transposes + 10 bf16 packs in one dispatch
  PPAll pp;
  pp.m[0]  = {enc_pw, ws + WS_ENCT, 64 * 1024, 10, 64, 1024};
  pp.m[1]  = {dec_pw, DECB, 1024 * 160, 0, 0, 0};  // bf16 [out][k]
  pp.m[2]  = {pri_w1, ws + WS_QW1T, 128 * 130, 10, 128, 130};
  pp.m[3]  = {pri_w2, ws + WS_QW2T, 128 * 128, 10, 128, 128};
  pp.m[4]  = {pri_w3, ws + WS_QW3T, 64 * 128, 10, 64, 128};
  pp.m[5]  = {pos_w1, ws + WS_PW1T, 128 * 192, 10, 128, 192};
  pp.m[6]  = {gru_wih, ws + WS_WIHT, 384 * 34, 10, 384, 34};
  pp.m[7]  = {pos_w1, WP1H, 128 * 128, 1, 0, 0};
  pp.m[8]  = {pos_w2, WP2, 128 * 128, 0, 0, 0};
  pp.m[9]  = {pos_w3, WP3, 64 * 128, 0, 0, 0};
  pp.m[10] = {gru_whh, WWHH, 384 * 128, 0, 0, 0};
  pp.m[11] = {gru_wih, WIHZ, 384 * 32, 2, 0, 0};
  pp.m[12] = {enc_w2, WC2, 16 * 64 * 32, 3, 64, 32};
  pp.m[13] = {enc_w3, WC3, 16 * 64 * 64, 3, 64, 64};
  pp.m[14] = {dec_w1, WD1, 16 * 64 * 64, 4, 64, 64};
  pp.m[15] = {dec_w2, WD2, 16 * 32 * 64, 4, 32, 64};
  hipLaunchKernelGGL(k_prep, dim3(32, 16), dim3(256), 0, stream, pp);

  // fused encoder (conv1..pre)
  k_enc<<<NF, 256, 0, stream>>>(obs, actions, enc_w1, enc_b1, WC2, enc_b2,
                                WC3, enc_b3, ws + WS_ENCT, enc_pb,
                                ws + WS_PW1T, pos_b1, ws + WS_WIHT, gru_bih,
                                POSL1E, GIA);

  // sequential core
  k_rssm4<<<NB, 512, 0, stream>>>(POSL1E, GIA, noise, WP1H, WP2, WP3, WWHH, WIHZ,
                                  pos_b2, pos_b3, gru_bhh, HS, out);

  // fused decoder (declin..deconv3) + prior
  k_dec<<<NF, 256, 0, stream>>>(HS, out + OUT_ZS, actions, DECB, dec_pb,
                                WD1, dec_b1, WD2, dec_b2, dec_w3, dec_b3,
                                ws + WS_QW1T, pri_b1, ws + WS_QW2T, pri_b2,
                                ws + WS_QW3T, pri_b3, out);
}